// Round 5
// baseline (8590.516 us; speedup 1.0000x reference)
//
#include <hip/hip_runtime.h>

// GRU (Flax GRUCell), B=64 T=512 D=512 H=512, fp32 in/out, fp16 MFMA compute.
//
// 8 groups x 8 batches; group g = 32 blocks with blockIdx%8==g. Per-step h
// exchange, two independent domains:
//   FAST (sc0, XCD-local L2): enabled only if all 32 blocks of the group
//     report the same HW_REG_XCC_ID (published via the proven sc1 transport).
//     Same XCC => same L2 => sc0 visibility is a hardware guarantee.
//     Polls still bounded; timeout => sticky escalation to slow.
//   SLOW (sc1, L3 coherence point; round-2-proven): published EVERY step by
//     wave 3 into separate buffers; depends only on own block's barrier.
// => no execution path can deadlock, no correctness dependence on placement.
// All inline-asm load outputs are EARLY-CLOBBER ("=&v") -- r4's crash was an
// output tuple overlapping the address pair.
// Block: 256 thr; w0..w2 = gate GEMMs (r,z,n); all waves dup the combine;
// w0 = fast publish, w1 = out stores, w3 = slow publish.
// Weight transpose done in-kernel (one-time) -> ws stays under the
// empirically-proven 36.87MB watermark. 256 blocks x 108KB LDS -> 1/CU.

#define BSZ 64
#define TLEN 512
#define DDIM 512
#define HDIM 512
#define NGRP 8
#define PBLK 32
#define GB 8
#define BH (BSZ * HDIM)
#define POLLB 65536
#define XCCB (1 << 18)

typedef _Float16 half8 __attribute__((ext_vector_type(8)));
typedef _Float16 half4v __attribute__((ext_vector_type(4)));
typedef _Float16 half2v __attribute__((ext_vector_type(2)));
typedef float f32x4 __attribute__((ext_vector_type(4)));

__device__ __forceinline__ float sigmf(float v) { return 1.f / (1.f + __expf(-v)); }

// ---------------- setup: x fp32->fp16; zero comm region
__global__ void gru_setup(const float* __restrict__ x, _Float16* __restrict__ xb,
                          unsigned* __restrict__ zbase) {
  size_t gid = (size_t)blockIdx.x * blockDim.x + threadIdx.x;
  size_t stride = (size_t)gridDim.x * blockDim.x;
  const float4* x4 = (const float4*)x;
  size_t nx4 = (size_t)BSZ * TLEN * DDIM / 4;
  for (size_t i = gid; i < nx4; i += stride) {
    float4 v = x4[i];
    half4v o = {(_Float16)v.x, (_Float16)v.y, (_Float16)v.z, (_Float16)v.w};
    *(half4v*)(xb + 4 * i) = o;
  }
  // zero exF(128K)+exS(128K)+flF(32K)+flS(32K)+xcc(32K) = 360448 B
  for (size_t i = gid; i < 90112; i += stride) zbase[i] = 0u;
}

// ---------------- recurrence
__global__ __launch_bounds__(256, 1) void gru_rec(
    const _Float16* __restrict__ xb, const float* __restrict__ Wi,
    const float* __restrict__ Wh, const float* __restrict__ bi,
    const float* __restrict__ bhn, _Float16* __restrict__ exF,
    _Float16* __restrict__ exS, unsigned* __restrict__ flF,
    unsigned* __restrict__ flS, unsigned* __restrict__ xccA,
    float* __restrict__ out) {
  // LDS: weights 2x48KB + gate tiles 2x2x3KB = 108KB -> 1 block/CU
  __shared__ _Float16 Wh_l[48 * 512];
  __shared__ _Float16 Wi_l[48 * 512];
  __shared__ float Gh_l[2][3 * 256];
  __shared__ float Gx_l[2][3 * 256];

  const int tid = threadIdx.x;
  const int lane = tid & 63;
  const int wid = tid >> 6;  // 0..2 = gate waves, 3 = slow publisher
  const int g = blockIdx.x & 7;
  const int rank = blockIdx.x >> 3;
  const int c0 = rank * 16;

  unsigned* const flFG = flF + g * (PBLK * 32);  // 128B-strided per-rank flags
  unsigned* const flSG = flS + g * (PBLK * 32);

  // publish XCC id early via the PROVEN sc1 transport (tag bit 8 = "valid")
  unsigned xcc;
  asm volatile("s_getreg_b32 %0, hwreg(HW_REG_XCC_ID)" : "=s"(xcc));
  xcc &= 255u;
  if (tid == 0)
    __hip_atomic_store(&xccA[blockIdx.x], xcc | 256u, __ATOMIC_RELAXED,
                       __HIP_MEMORY_SCOPE_AGENT);

  // --- one-time in-kernel weight transpose+convert into swizzled LDS.
  // element k of LDS row r lives at byte (r<<10) | (((k>>3)<<4)^((r&7)<<4)) | ((k&7)<<1)
  for (int idx = tid; idx < 48 * 512; idx += 256) {
    int k = idx / 48;
    int r = idx - k * 48;          // consecutive tid -> consecutive col (coalesced)
    int gate = r >> 4, j = r & 15;
    int col = gate * 512 + c0 + j;
    float vi = Wi[(size_t)k * 1536 + col];
    float vh = Wh[(size_t)k * 1536 + col];
    int phys = (r << 10) | ((((k >> 3) << 4) ^ ((r & 7) << 4))) | ((k & 7) << 1);
    *(_Float16*)((char*)Wi_l + phys) = (_Float16)vi;
    *(_Float16*)((char*)Wh_l + phys) = (_Float16)vh;
  }

  // combine-lane mapping (identical in all waves): batch m0, col pair cp
  const int m0 = lane >> 3;       // 0..7
  const int cp = (lane & 7) * 2;  // 0,2,...,14
  float bir[2], biz[2], bin_[2], bh2[2];
#pragma unroll
  for (int u = 0; u < 2; ++u) {
    bir[u] = bi[c0 + cp + u];
    biz[u] = bi[512 + c0 + cp + u];
    bin_[u] = bi[1024 + c0 + cp + u];
    bh2[u] = bhn[c0 + cp + u];
  }
  float hreg[2] = {0.f, 0.f};

  // --- fast-domain eligibility: all 32 group blocks on one XCC? (sc1 reads)
  bool slow = false;
  if (wid < 3) {
    const unsigned* xp = &xccA[(lane & 31) * 8 + g];
    bool ok = false;
    for (int it = 0; it < XCCB && !ok; ++it) {
      unsigned v = __hip_atomic_load(xp, __ATOMIC_RELAXED, __HIP_MEMORY_SCOPE_AGENT);
      ok = (bool)__all(v >= 256u);
    }
    if (ok) {
      unsigned v = __hip_atomic_load(xp, __ATOMIC_RELAXED, __HIP_MEMORY_SCOPE_AGENT);
      slow = !__all((v & 255u) == xcc);
    } else {
      slow = true;
    }
  }
  __syncthreads();  // weights staged

  const int ar = lane & 15;  // MFMA A row / B col-in-slice
  const int kg = lane >> 4;  // k-group
  const int wrow = wid * 16 + ar;
  const int mb = g * GB + (ar & 7);  // batch this lane loads (rows 8..15 dup)
  const _Float16* const xrow = xb + (size_t)mb * (TLEN * DDIM);

  for (int t = 0; t < TLEN; ++t) {
    if (wid < 3) {
      // 1. prefetch x fragments (plain cached loads)
      half8 a_x[16];
      const half8* xs = (const half8*)(xrow + (size_t)t * DDIM);
#pragma unroll
      for (int kt = 0; kt < 16; ++kt) a_x[kt] = xs[kt * 4 + kg];

      // 2. wait for h(t): bounded fast poll (sticky escalation), else slow poll
      if (t > 0) {
        if (!slow) {
          const unsigned* pf = &flFG[(lane & 31) * 32];
          bool got = false;
          for (int it = 0; it < POLLB; ++it) {
            unsigned v;
            asm volatile("global_load_dword %0, %1, off sc0\n\ts_waitcnt vmcnt(0)"
                         : "=&v"(v)
                         : "v"(pf));
            if (__all(v >= (unsigned)(t + 1))) { got = true; break; }
          }
          if (!got) slow = true;  // permanent escalation; slow domain always live
        }
        if (slow) {
          const unsigned* ps = &flSG[(lane & 31) * 32];
          while (true) {
            unsigned v = __hip_atomic_load(ps, __ATOMIC_RELAXED, __HIP_MEMORY_SCOPE_AGENT);
            if (__all(v >= (unsigned)(t + 1))) break;
          }
        }
      }

      // 3. issue h loads (fast: sc0 asm, EARLY-CLOBBER outputs; slow: sc1)
      half8 ah[16];
      if (t > 0) {
        if (!slow) {
          const _Float16* hp = exF + (size_t)(t & 1) * BH + (size_t)mb * HDIM + kg * 8;
          asm volatile(
              "global_load_dwordx4 %0,  %16, off sc0\n\t"
              "global_load_dwordx4 %1,  %16, off offset:64 sc0\n\t"
              "global_load_dwordx4 %2,  %16, off offset:128 sc0\n\t"
              "global_load_dwordx4 %3,  %16, off offset:192 sc0\n\t"
              "global_load_dwordx4 %4,  %16, off offset:256 sc0\n\t"
              "global_load_dwordx4 %5,  %16, off offset:320 sc0\n\t"
              "global_load_dwordx4 %6,  %16, off offset:384 sc0\n\t"
              "global_load_dwordx4 %7,  %16, off offset:448 sc0\n\t"
              "global_load_dwordx4 %8,  %16, off offset:512 sc0\n\t"
              "global_load_dwordx4 %9,  %16, off offset:576 sc0\n\t"
              "global_load_dwordx4 %10, %16, off offset:640 sc0\n\t"
              "global_load_dwordx4 %11, %16, off offset:704 sc0\n\t"
              "global_load_dwordx4 %12, %16, off offset:768 sc0\n\t"
              "global_load_dwordx4 %13, %16, off offset:832 sc0\n\t"
              "global_load_dwordx4 %14, %16, off offset:896 sc0\n\t"
              "global_load_dwordx4 %15, %16, off offset:960 sc0"
              : "=&v"(ah[0]), "=&v"(ah[1]), "=&v"(ah[2]), "=&v"(ah[3]),
                "=&v"(ah[4]), "=&v"(ah[5]), "=&v"(ah[6]), "=&v"(ah[7]),
                "=&v"(ah[8]), "=&v"(ah[9]), "=&v"(ah[10]), "=&v"(ah[11]),
                "=&v"(ah[12]), "=&v"(ah[13]), "=&v"(ah[14]), "=&v"(ah[15])
              : "v"(hp));
        } else {
          const unsigned long long* hq =
              (const unsigned long long*)(exS + (size_t)(t & 1) * BH +
                                          (size_t)mb * HDIM + kg * 8);
#pragma unroll
          for (int kt = 0; kt < 16; ++kt) {
            unsigned long long lo = __hip_atomic_load(hq + (size_t)kt * 8,
                                                      __ATOMIC_RELAXED, __HIP_MEMORY_SCOPE_AGENT);
            unsigned long long hi = __hip_atomic_load(hq + (size_t)kt * 8 + 1,
                                                      __ATOMIC_RELAXED, __HIP_MEMORY_SCOPE_AGENT);
            struct { unsigned long long a, b; } t2 = {lo, hi};
            __builtin_memcpy(&ah[kt], &t2, 16);
          }
        }
      }

      // 4. x-side MFMAs (hide h-load latency under them)
      f32x4 acc_x = {0.f, 0.f, 0.f, 0.f};
      f32x4 acc_h = {0.f, 0.f, 0.f, 0.f};
#pragma unroll
      for (int kt = 0; kt < 16; ++kt) {
        const int off = (((kt * 4 + kg) << 4) ^ ((ar & 7) << 4));
        half8 b_i = *(const half8*)((const char*)Wi_l + (wrow << 10) + off);
        acc_x = __builtin_amdgcn_mfma_f32_16x16x32_f16(a_x[kt], b_i, acc_x, 0, 0, 0);
      }

      // 5. h-side MFMAs (fast path: drain loads, fence MFMA hoisting -- rule 18)
      if (t > 0) {
        if (!slow) {
          asm volatile("s_waitcnt vmcnt(0)" ::: "memory");
          __builtin_amdgcn_sched_barrier(0);
        }
#pragma unroll
        for (int kt = 0; kt < 16; ++kt) {
          const int off = (((kt * 4 + kg) << 4) ^ ((ar & 7) << 4));
          half8 b_h = *(const half8*)((const char*)Wh_l + (wrow << 10) + off);
          acc_h = __builtin_amdgcn_mfma_f32_16x16x32_f16(ah[kt], b_h, acc_h, 0, 0, 0);
        }
      }

      // 6. publish gate tile (double-buffered; D layout col=ar, row=kg*4+q)
#pragma unroll
      for (int q = 0; q < 4; ++q) {
        int row = kg * 4 + q;
        Gh_l[t & 1][wid * 256 + row * 16 + ar] = acc_h[q];
        Gx_l[t & 1][wid * 256 + row * 16 + ar] = acc_x[q];
      }
    }
    __syncthreads();  // gates(t) ready

    // 7. combine -- duplicated in ALL waves (identical -> deterministic)
    const float* GhT = Gh_l[t & 1];
    const float* GxT = Gx_l[t & 1];
    float hnew[2];
#pragma unroll
    for (int u = 0; u < 2; ++u) {
      const int gi_ = m0 * 16 + cp + u;
      float r = sigmf(GxT[gi_] + GhT[gi_] + bir[u]);
      float z = sigmf(GxT[256 + gi_] + GhT[256 + gi_] + biz[u]);
      float pren = GxT[512 + gi_] + bin_[u] + r * (GhT[512 + gi_] + bh2[u]);
      float n = 2.f / (1.f + __expf(-2.f * pren)) - 1.f;
      hnew[u] = (1.f - z) * n + z * hreg[u];
      hreg[u] = hnew[u];
    }
    const int b = g * GB + m0;

    // 8. role-split epilogues (flag value = t+2; pollers at step t' want t'+1)
    if (wid == 0) {  // FAST publish: sc0 data -> drain -> sc0 flag
      half2v p2 = {(_Float16)hnew[0], (_Float16)hnew[1]};
      unsigned pu;
      __builtin_memcpy(&pu, &p2, 4);
      unsigned* dst =
          (unsigned*)(exF + (size_t)((t + 1) & 1) * BH + (size_t)b * HDIM + c0 + cp);
      asm volatile("global_store_dword %0, %1, off sc0" ::"v"(dst), "v"(pu) : "memory");
      asm volatile("s_waitcnt vmcnt(0)" ::: "memory");
      if (lane == 0) {
        unsigned fv = (unsigned)(t + 2);
        asm volatile("global_store_dword %0, %1, off sc0" ::"v"(&flFG[rank * 32]),
                     "v"(fv)
                     : "memory");
      }
    } else if (wid == 1) {  // output stores (off critical path)
      *(float2*)(out + ((size_t)b * TLEN + t) * HDIM + c0 + cp) =
          make_float2(hnew[0], hnew[1]);
    } else if (wid == 3) {  // SLOW publish: sc1 data -> drain -> sc1 flag
      half2v p2 = {(_Float16)hnew[0], (_Float16)hnew[1]};
      unsigned pu;
      __builtin_memcpy(&pu, &p2, 4);
      __hip_atomic_store(
          (unsigned*)(exS + (size_t)((t + 1) & 1) * BH + (size_t)b * HDIM + c0 + cp),
          pu, __ATOMIC_RELAXED, __HIP_MEMORY_SCOPE_AGENT);
      asm volatile("s_waitcnt vmcnt(0)" ::: "memory");
      if (lane == 0)
        __hip_atomic_store(&flSG[rank * 32], (unsigned)(t + 2), __ATOMIC_RELAXED,
                           __HIP_MEMORY_SCOPE_AGENT);
    }
  }

  // carry output: final h
  if (wid == 1) {
    const int b = g * GB + m0;
    *(float2*)(out + (size_t)BSZ * TLEN * HDIM + (size_t)b * HDIM + c0 + cp) =
        make_float2(hreg[0], hreg[1]);
  }
}

extern "C" void kernel_launch(void* const* d_in, const int* in_sizes, int n_in,
                              void* d_out, int out_size, void* d_ws, size_t ws_size,
                              hipStream_t stream) {
  const float* x = (const float*)d_in[0];
  const float* Wi = (const float*)d_in[1];
  const float* bi = (const float*)d_in[2];
  const float* Wh = (const float*)d_in[3];
  const float* bhn = (const float*)d_in[4];
  float* out = (float*)d_out;

  // ws layout (bytes), total 33,914,880 (< 36.87MB proven watermark):
  // xb 33554432 | exF 131072 | exS 131072 | flF 32768 | flS 32768 | xcc 32768
  char* ws = (char*)d_ws;
  _Float16* xb = (_Float16*)ws;
  _Float16* exF = (_Float16*)(ws + 33554432);
  _Float16* exS = (_Float16*)(ws + 33685504);
  unsigned* flF = (unsigned*)(ws + 33816576);
  unsigned* flS = (unsigned*)(ws + 33849344);
  unsigned* xccA = (unsigned*)(ws + 33882112);

  gru_setup<<<4096, 256, 0, stream>>>(x, xb, (unsigned*)(ws + 33554432));
  gru_rec<<<NGRP * PBLK, 256, 0, stream>>>(xb, Wi, Wh, bi, bhn, exF, exS, flF, flS,
                                           xccA, out);
}

// Round 6
// 3427.287 us; speedup vs baseline: 2.5065x; 2.5065x over previous
//
#include <hip/hip_runtime.h>

// GRU (Flax GRUCell), B=64 T=512 D=512 H=512, fp32 in/out, fp16 MFMA compute.
//
// 4 groups x 16 batches x 32 blocks (r2-proven topology). Per-step h exchange
// uses SENTINEL-CODED DATA POLLING over the r2-proven sc1/agent transport:
// |h|<1 strictly, so fp16 0x4000 (2.0) is unreachable -- readers poll the
// exchange data itself (16B chunks) until sentinel-free; operands are then
// already in MFMA registers. No flags, no vmcnt on the publish path -> one
// L3 round trip per step instead of ~3. 4-slot buffer rotation; owner resets
// its own region 2 slots ahead (drift bound <=1 step makes this safe; all
// cross-wave ordering via the compiler's vmcnt(0)-before-s_barrier).
// Poll loops bounded -> worst case visible wrong answer, never a hang.
// Block: 192 thr, wave w = gate w (r,z,n); wave 0 combines + publishes;
// wave 1 resets. 128 blocks x 108KB LDS -> 1 block/CU, all co-resident.

#define BSZ 64
#define TLEN 512
#define DDIM 512
#define HDIM 512
#define NGRP 4
#define PBLK 32
#define GB 16
#define SLOTB 16384   // bytes per slot per group: 32 ranks * 512B
#define GRPB 65536    // 4 slots
#define SENT32 0x40004000u
#define GUARD (1 << 18)

typedef _Float16 half8 __attribute__((ext_vector_type(8)));
typedef _Float16 half4v __attribute__((ext_vector_type(4)));
typedef float f32x4 __attribute__((ext_vector_type(4)));

__device__ __forceinline__ float sigmf(float v) { return 1.f / (1.f + __expf(-v)); }

// ---------------- setup: x fp32->fp16; fill exchange with sentinel
__global__ void gru_setup(const float* __restrict__ x, _Float16* __restrict__ xb,
                          unsigned* __restrict__ exch) {
  size_t gid = (size_t)blockIdx.x * blockDim.x + threadIdx.x;
  size_t stride = (size_t)gridDim.x * blockDim.x;
  const float4* x4 = (const float4*)x;
  size_t nx4 = (size_t)BSZ * TLEN * DDIM / 4;
  for (size_t i = gid; i < nx4; i += stride) {
    float4 v = x4[i];
    half4v o = {(_Float16)v.x, (_Float16)v.y, (_Float16)v.z, (_Float16)v.w};
    *(half4v*)(xb + 4 * i) = o;
  }
  for (size_t i = gid; i < (size_t)NGRP * GRPB / 4; i += stride) exch[i] = SENT32;
}

// dirty-chunk mask: dword low half == sentinel? (each 4B writer store covers
// 2 fp16 atomically, so per-dword low-half check is partial-write-safe)
__device__ __forceinline__ unsigned chk16(const half8* ah) {
  unsigned dirty = 0;
#pragma unroll
  for (int kt = 0; kt < 16; ++kt) {
    uint4 c;
    __builtin_memcpy(&c, &ah[kt], 16);
    unsigned bad = ((c.x & 0xFFFFu) == 0x4000u) | ((c.y & 0xFFFFu) == 0x4000u) |
                   ((c.z & 0xFFFFu) == 0x4000u) | ((c.w & 0xFFFFu) == 0x4000u);
    dirty |= bad << kt;
  }
  return dirty;
}

// ---------------- recurrence
__global__ __launch_bounds__(192, 1) void gru_rec(
    const _Float16* __restrict__ xb, const float* __restrict__ Wi,
    const float* __restrict__ Wh, const float* __restrict__ bi,
    const float* __restrict__ bhn, char* __restrict__ exch,
    float* __restrict__ out) {
  // LDS: weights 2x48KB + gate tiles 2x2x3KB = 108KB -> 1 block/CU
  __shared__ _Float16 Wh_l[48 * 512];
  __shared__ _Float16 Wi_l[48 * 512];
  __shared__ float Gh_l[2][3 * 256];
  __shared__ float Gx_l[2][3 * 256];

  const int tid = threadIdx.x;
  const int lane = tid & 63;
  const int wid = tid >> 6;  // gate index; w1 also resets
  const int g = blockIdx.x >> 5;
  const int rank = blockIdx.x & 31;
  const int c0 = rank * 16;
  char* const exg = exch + (size_t)g * GRPB;

  // --- one-time in-kernel weight transpose+convert into swizzled LDS (r5-proven)
  // element k of row r at byte (r<<10) | (((k>>3)<<4)^((r&7)<<4)) | ((k&7)<<1)
  for (int idx = tid; idx < 48 * 512; idx += 192) {
    int k = idx / 48;
    int r = idx - k * 48;
    int gate = r >> 4, j = r & 15;
    int col = gate * 512 + c0 + j;
    int phys = (r << 10) | ((((k >> 3) << 4) ^ ((r & 7) << 4))) | ((k & 7) << 1);
    *(_Float16*)((char*)Wi_l + phys) = (_Float16)Wi[(size_t)k * 1536 + col];
    *(_Float16*)((char*)Wh_l + phys) = (_Float16)Wh[(size_t)k * 1536 + col];
  }

  // combine-lane mapping (wave0): batches {m0, m0+8}, cols {cp, cp+1}
  const int m0 = lane >> 3;       // 0..7
  const int cp = (lane & 7) * 2;  // 0,2,...,14
  float bir[2], biz[2], bin_[2], bh2[2];
#pragma unroll
  for (int u = 0; u < 2; ++u) {
    bir[u] = bi[c0 + cp + u];
    biz[u] = bi[512 + c0 + cp + u];
    bin_[u] = bi[1024 + c0 + cp + u];
    bh2[u] = bhn[c0 + cp + u];
  }
  float hreg[2][2] = {{0.f, 0.f}, {0.f, 0.f}};
  __syncthreads();  // weights staged

  const int ar = lane & 15;  // A row (batch) / B col-in-slice
  const int kg = lane >> 4;  // k-group
  const int wrow = wid * 16 + ar;
  const int mbat = g * GB + ar;
  const _Float16* const xrow = xb + (size_t)mbat * (TLEN * DDIM);
  // reader chunk kt lives at hbase + slot*SLOTB + kt*1024
  char* const hbase = exg + ((kg >> 1) * 512 + ar * 32 + (kg & 1) * 16);

  for (int t = 0; t < TLEN; ++t) {
    // 0. wave1: reset own region in slot (t+2)&3 (fire-and-forget; acked at
    //    this step's barrier, published into only at end of step t+1)
    if (wid == 1) {
      unsigned* rst = (unsigned*)(exg + ((t + 2) & 3) * SLOTB + rank * 512);
      __hip_atomic_store(rst + lane, SENT32, __ATOMIC_RELAXED, __HIP_MEMORY_SCOPE_AGENT);
      __hip_atomic_store(rst + 64 + lane, SENT32, __ATOMIC_RELAXED,
                         __HIP_MEMORY_SCOPE_AGENT);
    }

    // 1. prefetch x fragments (plain cached loads)
    half8 a_x[16];
    const half8* xs = (const half8*)(xrow + (size_t)t * DDIM);
#pragma unroll
    for (int kt = 0; kt < 16; ++kt) a_x[kt] = xs[kt * 4 + kg];

    // 2. data-poll h(t) from slot t&3 (skip t=0: h=0)
    half8 ah[16];
    if (t > 0) {
      char* hb = hbase + (t & 3) * SLOTB;
      const char* p0 = hb;
      const char* p1 = hb + 4096;
      const char* p2 = hb + 8192;
      const char* p3 = hb + 12288;
      asm volatile(
          "global_load_dwordx4 %0,  %16, off sc1\n\t"
          "global_load_dwordx4 %1,  %16, off offset:1024 sc1\n\t"
          "global_load_dwordx4 %2,  %16, off offset:2048 sc1\n\t"
          "global_load_dwordx4 %3,  %16, off offset:3072 sc1\n\t"
          "global_load_dwordx4 %4,  %17, off sc1\n\t"
          "global_load_dwordx4 %5,  %17, off offset:1024 sc1\n\t"
          "global_load_dwordx4 %6,  %17, off offset:2048 sc1\n\t"
          "global_load_dwordx4 %7,  %17, off offset:3072 sc1\n\t"
          "global_load_dwordx4 %8,  %18, off sc1\n\t"
          "global_load_dwordx4 %9,  %18, off offset:1024 sc1\n\t"
          "global_load_dwordx4 %10, %18, off offset:2048 sc1\n\t"
          "global_load_dwordx4 %11, %18, off offset:3072 sc1\n\t"
          "global_load_dwordx4 %12, %19, off sc1\n\t"
          "global_load_dwordx4 %13, %19, off offset:1024 sc1\n\t"
          "global_load_dwordx4 %14, %19, off offset:2048 sc1\n\t"
          "global_load_dwordx4 %15, %19, off offset:3072 sc1\n\t"
          "s_waitcnt vmcnt(0)"
          : "=&v"(ah[0]), "=&v"(ah[1]), "=&v"(ah[2]), "=&v"(ah[3]), "=&v"(ah[4]),
            "=&v"(ah[5]), "=&v"(ah[6]), "=&v"(ah[7]), "=&v"(ah[8]), "=&v"(ah[9]),
            "=&v"(ah[10]), "=&v"(ah[11]), "=&v"(ah[12]), "=&v"(ah[13]),
            "=&v"(ah[14]), "=&v"(ah[15])
          : "v"(p0), "v"(p1), "v"(p2), "v"(p3));
      unsigned dirty = chk16(ah);
      int guard = 0;
      while (__any(dirty != 0u)) {
        if (++guard > GUARD) break;  // bounded: visible failure, never a hang
#pragma unroll
        for (int kt = 0; kt < 16; ++kt) {
          if ((dirty >> kt) & 1u) {
            asm volatile("global_load_dwordx4 %0, %1, off sc1\n\ts_waitcnt vmcnt(0)"
                         : "=&v"(ah[kt])
                         : "v"(hb + kt * 1024));
          }
        }
        dirty = chk16(ah);
      }
    }

    // 3. MFMAs: x-side then h-side (operands already in registers)
    f32x4 acc_x = {0.f, 0.f, 0.f, 0.f};
    f32x4 acc_h = {0.f, 0.f, 0.f, 0.f};
#pragma unroll
    for (int kt = 0; kt < 16; ++kt) {
      const int off = (((kt * 4 + kg) << 4) ^ ((ar & 7) << 4));
      half8 b_i = *(const half8*)((const char*)Wi_l + (wrow << 10) + off);
      acc_x = __builtin_amdgcn_mfma_f32_16x16x32_f16(a_x[kt], b_i, acc_x, 0, 0, 0);
    }
    if (t > 0) {
      __builtin_amdgcn_sched_barrier(0);
#pragma unroll
      for (int kt = 0; kt < 16; ++kt) {
        const int off = (((kt * 4 + kg) << 4) ^ ((ar & 7) << 4));
        half8 b_h = *(const half8*)((const char*)Wh_l + (wrow << 10) + off);
        acc_h = __builtin_amdgcn_mfma_f32_16x16x32_f16(ah[kt], b_h, acc_h, 0, 0, 0);
      }
    }

    // 4. publish gate tiles (double-buffered; D layout col=ar, row=kg*4+q)
#pragma unroll
    for (int q = 0; q < 4; ++q) {
      int row = kg * 4 + q;
      Gh_l[t & 1][wid * 256 + row * 16 + ar] = acc_h[q];
      Gx_l[t & 1][wid * 256 + row * 16 + ar] = acc_x[q];
    }
    __syncthreads();

    // 5. combine + publish (wave 0): fire-and-forget sentinel-coded data
    if (wid == 0) {
      const float* GhT = Gh_l[t & 1];
      const float* GxT = Gx_l[t & 1];
      char* pub = exg + ((t + 1) & 3) * SLOTB + rank * 512;
      float hn2[2][2];
#pragma unroll
      for (int bsel = 0; bsel < 2; ++bsel) {
        const int m = m0 + 8 * bsel;
#pragma unroll
        for (int u = 0; u < 2; ++u) {
          const int gi_ = m * 16 + cp + u;
          float r = sigmf(GxT[gi_] + GhT[gi_] + bir[u]);
          float z = sigmf(GxT[256 + gi_] + GhT[256 + gi_] + biz[u]);
          float pren = GxT[512 + gi_] + bin_[u] + r * (GhT[512 + gi_] + bh2[u]);
          float n = 2.f / (1.f + __expf(-2.f * pren)) - 1.f;
          hn2[bsel][u] = (1.f - z) * n + z * hreg[bsel][u];
          hreg[bsel][u] = hn2[bsel][u];
        }
        _Float16 q0 = (_Float16)hn2[bsel][0], q1 = (_Float16)hn2[bsel][1];
        unsigned pu = ((unsigned)*(unsigned short*)&q1 << 16) | *(unsigned short*)&q0;
        __hip_atomic_store((unsigned*)(pub + m * 32 + cp * 2), pu, __ATOMIC_RELAXED,
                           __HIP_MEMORY_SCOPE_AGENT);
      }
      // out stores after the publishes (off the critical path)
#pragma unroll
      for (int bsel = 0; bsel < 2; ++bsel) {
        const int b = g * GB + m0 + 8 * bsel;
        *(float2*)(out + ((size_t)b * TLEN + t) * HDIM + c0 + cp) =
            make_float2(hn2[bsel][0], hn2[bsel][1]);
      }
    }
  }

  // carry output: final h
  if (wid == 0) {
#pragma unroll
    for (int bsel = 0; bsel < 2; ++bsel) {
      const int b = g * GB + m0 + 8 * bsel;
      *(float2*)(out + (size_t)BSZ * TLEN * HDIM + (size_t)b * HDIM + c0 + cp) =
          make_float2(hreg[bsel][0], hreg[bsel][1]);
    }
  }
}

extern "C" void kernel_launch(void* const* d_in, const int* in_sizes, int n_in,
                              void* d_out, int out_size, void* d_ws, size_t ws_size,
                              hipStream_t stream) {
  const float* x = (const float*)d_in[0];
  const float* Wi = (const float*)d_in[1];
  const float* bi = (const float*)d_in[2];
  const float* Wh = (const float*)d_in[3];
  const float* bhn = (const float*)d_in[4];
  float* out = (float*)d_out;

  // ws layout (bytes): xb 33554432 | exch 262144  (total 33.8MB, proven-safe)
  char* ws = (char*)d_ws;
  _Float16* xb = (_Float16*)ws;
  char* exch = ws + 33554432;

  gru_setup<<<4096, 256, 0, stream>>>(x, xb, (unsigned*)exch);
  gru_rec<<<NGRP * PBLK, 192, 0, stream>>>(xb, Wi, Wh, bi, bhn, exch, out);
}

// Round 7
// 2173.310 us; speedup vs baseline: 3.9527x; 1.5770x over previous
//
#include <hip/hip_runtime.h>

// GRU (Flax GRUCell), B=64 T=512 D=512 H=512, fp32 in/out, fp16 MFMA compute.
//
// 4 groups x 16 batches x 32 blocks. Per-step h exchange via SENTINEL-CODED
// DATA POLLING on the sc1/agent transport (r6-proven): |h|<1 strictly, so
// fp16 0x4000 (2.0) is unreachable; readers poll the exchange data itself
// until sentinel-free -- operands then already sit in MFMA registers. No
// flags, no publish-side vmcnt. 4-slot rotation; owner resets its own region
// 2 slots ahead (drift bound <=1 step; hazard-freedom argued in r6, held on
// HW). r7 change: EVERY poll sweep is fully pipelined (16 loads, ONE
// vmcnt(0)) -- r6's serialized per-chunk retry (16 x ~400cy per sweep) was
// the regression. Poll loops bounded -> never a hang.
// Block: 192 thr, wave w = gate w (r,z,n); wave 0 combines + publishes;
// wave 1 resets. 128 blocks x 108KB LDS -> 1 block/CU, all co-resident.

#define BSZ 64
#define TLEN 512
#define DDIM 512
#define HDIM 512
#define NGRP 4
#define PBLK 32
#define GB 16
#define SLOTB 16384   // bytes per slot per group: 32 ranks * 512B
#define GRPB 65536    // 4 slots
#define SENT32 0x40004000u
#define GUARD (1 << 16)

typedef _Float16 half8 __attribute__((ext_vector_type(8)));
typedef _Float16 half4v __attribute__((ext_vector_type(4)));
typedef float f32x4 __attribute__((ext_vector_type(4)));

__device__ __forceinline__ float sigmf(float v) { return 1.f / (1.f + __expf(-v)); }

// ---------------- setup: x fp32->fp16; fill exchange with sentinel
__global__ void gru_setup(const float* __restrict__ x, _Float16* __restrict__ xb,
                          unsigned* __restrict__ exch) {
  size_t gid = (size_t)blockIdx.x * blockDim.x + threadIdx.x;
  size_t stride = (size_t)gridDim.x * blockDim.x;
  const float4* x4 = (const float4*)x;
  size_t nx4 = (size_t)BSZ * TLEN * DDIM / 4;
  for (size_t i = gid; i < nx4; i += stride) {
    float4 v = x4[i];
    half4v o = {(_Float16)v.x, (_Float16)v.y, (_Float16)v.z, (_Float16)v.w};
    *(half4v*)(xb + 4 * i) = o;
  }
  for (size_t i = gid; i < (size_t)NGRP * GRPB / 4; i += stride) exch[i] = SENT32;
}

// dirty-chunk mask: dword low half == sentinel? (each 4B writer store covers
// 2 fp16 atomically, so per-dword low-half check is partial-write-safe)
__device__ __forceinline__ unsigned chk16(const half8* ah) {
  unsigned dirty = 0;
#pragma unroll
  for (int kt = 0; kt < 16; ++kt) {
    uint4 c;
    __builtin_memcpy(&c, &ah[kt], 16);
    unsigned bad = ((c.x & 0xFFFFu) == 0x4000u) | ((c.y & 0xFFFFu) == 0x4000u) |
                   ((c.z & 0xFFFFu) == 0x4000u) | ((c.w & 0xFFFFu) == 0x4000u);
    dirty |= bad << kt;
  }
  return dirty;
}

// ---------------- recurrence
__global__ __launch_bounds__(192, 1) void gru_rec(
    const _Float16* __restrict__ xb, const float* __restrict__ Wi,
    const float* __restrict__ Wh, const float* __restrict__ bi,
    const float* __restrict__ bhn, char* __restrict__ exch,
    float* __restrict__ out) {
  // LDS: weights 2x48KB + gate tiles 2x2x3KB = 108KB -> 1 block/CU
  __shared__ _Float16 Wh_l[48 * 512];
  __shared__ _Float16 Wi_l[48 * 512];
  __shared__ float Gh_l[2][3 * 256];
  __shared__ float Gx_l[2][3 * 256];

  const int tid = threadIdx.x;
  const int lane = tid & 63;
  const int wid = tid >> 6;  // gate index; w1 also resets
  const int g = blockIdx.x >> 5;
  const int rank = blockIdx.x & 31;
  const int c0 = rank * 16;
  char* const exg = exch + (size_t)g * GRPB;

  // --- one-time in-kernel weight transpose+convert into swizzled LDS
  // element k of row r at byte (r<<10) | (((k>>3)<<4)^((r&7)<<4)) | ((k&7)<<1)
  for (int idx = tid; idx < 48 * 512; idx += 192) {
    int k = idx / 48;
    int r = idx - k * 48;
    int gate = r >> 4, j = r & 15;
    int col = gate * 512 + c0 + j;
    int phys = (r << 10) | ((((k >> 3) << 4) ^ ((r & 7) << 4))) | ((k & 7) << 1);
    *(_Float16*)((char*)Wi_l + phys) = (_Float16)Wi[(size_t)k * 1536 + col];
    *(_Float16*)((char*)Wh_l + phys) = (_Float16)Wh[(size_t)k * 1536 + col];
  }

  // combine-lane mapping (wave0): batches {m0, m0+8}, cols {cp, cp+1}
  const int m0 = lane >> 3;       // 0..7
  const int cp = (lane & 7) * 2;  // 0,2,...,14
  float bir[2], biz[2], bin_[2], bh2[2];
#pragma unroll
  for (int u = 0; u < 2; ++u) {
    bir[u] = bi[c0 + cp + u];
    biz[u] = bi[512 + c0 + cp + u];
    bin_[u] = bi[1024 + c0 + cp + u];
    bh2[u] = bhn[c0 + cp + u];
  }
  float hreg[2][2] = {{0.f, 0.f}, {0.f, 0.f}};
  __syncthreads();  // weights staged

  const int ar = lane & 15;  // A row (batch) / B col-in-slice
  const int kg = lane >> 4;  // k-group
  const int wrow = wid * 16 + ar;
  const int mbat = g * GB + ar;
  const _Float16* const xrow = xb + (size_t)mbat * (TLEN * DDIM);
  // reader chunk kt lives at hbase + slot*SLOTB + kt*1024
  char* const hbase = exg + ((kg >> 1) * 512 + ar * 32 + (kg & 1) * 16);

  for (int t = 0; t < TLEN; ++t) {
    // 0. wave1: reset own region in slot (t+2)&3 (fire-and-forget; acked by
    //    this wave's vmcnt(0) at the step barrier; slot republished only at
    //    end of step t+1 -> ordered)
    if (wid == 1) {
      unsigned* rst = (unsigned*)(exg + ((t + 2) & 3) * SLOTB + rank * 512);
      __hip_atomic_store(rst + lane, SENT32, __ATOMIC_RELAXED, __HIP_MEMORY_SCOPE_AGENT);
      __hip_atomic_store(rst + 64 + lane, SENT32, __ATOMIC_RELAXED,
                         __HIP_MEMORY_SCOPE_AGENT);
    }

    // 1. prefetch x fragments (plain cached loads)
    half8 a_x[16];
    const half8* xs = (const half8*)(xrow + (size_t)t * DDIM);
#pragma unroll
    for (int kt = 0; kt < 16; ++kt) a_x[kt] = xs[kt * 4 + kg];

    // 2. data-poll h(t) from slot t&3 (skip t=0: h=0). EVERY sweep is the
    //    fully-pipelined 16-load block with a single vmcnt(0).
    half8 ah[16];
    if (t > 0) {
      char* hb = hbase + (t & 3) * SLOTB;
      const char* p0 = hb;
      const char* p1 = hb + 4096;
      const char* p2 = hb + 8192;
      const char* p3 = hb + 12288;
      unsigned dirty;
      int guard = 0;
      do {
        asm volatile(
            "global_load_dwordx4 %0,  %16, off sc1\n\t"
            "global_load_dwordx4 %1,  %16, off offset:1024 sc1\n\t"
            "global_load_dwordx4 %2,  %16, off offset:2048 sc1\n\t"
            "global_load_dwordx4 %3,  %16, off offset:3072 sc1\n\t"
            "global_load_dwordx4 %4,  %17, off sc1\n\t"
            "global_load_dwordx4 %5,  %17, off offset:1024 sc1\n\t"
            "global_load_dwordx4 %6,  %17, off offset:2048 sc1\n\t"
            "global_load_dwordx4 %7,  %17, off offset:3072 sc1\n\t"
            "global_load_dwordx4 %8,  %18, off sc1\n\t"
            "global_load_dwordx4 %9,  %18, off offset:1024 sc1\n\t"
            "global_load_dwordx4 %10, %18, off offset:2048 sc1\n\t"
            "global_load_dwordx4 %11, %18, off offset:3072 sc1\n\t"
            "global_load_dwordx4 %12, %19, off sc1\n\t"
            "global_load_dwordx4 %13, %19, off offset:1024 sc1\n\t"
            "global_load_dwordx4 %14, %19, off offset:2048 sc1\n\t"
            "global_load_dwordx4 %15, %19, off offset:3072 sc1\n\t"
            "s_waitcnt vmcnt(0)"
            : "=&v"(ah[0]), "=&v"(ah[1]), "=&v"(ah[2]), "=&v"(ah[3]),
              "=&v"(ah[4]), "=&v"(ah[5]), "=&v"(ah[6]), "=&v"(ah[7]),
              "=&v"(ah[8]), "=&v"(ah[9]), "=&v"(ah[10]), "=&v"(ah[11]),
              "=&v"(ah[12]), "=&v"(ah[13]), "=&v"(ah[14]), "=&v"(ah[15])
            : "v"(p0), "v"(p1), "v"(p2), "v"(p3));
        dirty = chk16(ah);
      } while (__any(dirty != 0u) && ++guard < GUARD);  // bounded: no hang
    }

    // 3. MFMAs: x-side then h-side (operands already in registers)
    f32x4 acc_x = {0.f, 0.f, 0.f, 0.f};
    f32x4 acc_h = {0.f, 0.f, 0.f, 0.f};
#pragma unroll
    for (int kt = 0; kt < 16; ++kt) {
      const int off = (((kt * 4 + kg) << 4) ^ ((ar & 7) << 4));
      half8 b_i = *(const half8*)((const char*)Wi_l + (wrow << 10) + off);
      acc_x = __builtin_amdgcn_mfma_f32_16x16x32_f16(a_x[kt], b_i, acc_x, 0, 0, 0);
    }
    if (t > 0) {
      __builtin_amdgcn_sched_barrier(0);
#pragma unroll
      for (int kt = 0; kt < 16; ++kt) {
        const int off = (((kt * 4 + kg) << 4) ^ ((ar & 7) << 4));
        half8 b_h = *(const half8*)((const char*)Wh_l + (wrow << 10) + off);
        acc_h = __builtin_amdgcn_mfma_f32_16x16x32_f16(ah[kt], b_h, acc_h, 0, 0, 0);
      }
    }

    // 4. publish gate tiles (double-buffered; D layout col=ar, row=kg*4+q)
#pragma unroll
    for (int q = 0; q < 4; ++q) {
      int row = kg * 4 + q;
      Gh_l[t & 1][wid * 256 + row * 16 + ar] = acc_h[q];
      Gx_l[t & 1][wid * 256 + row * 16 + ar] = acc_x[q];
    }
    __syncthreads();

    // 5. combine + publish (wave 0): fire-and-forget sentinel-coded data
    if (wid == 0) {
      const float* GhT = Gh_l[t & 1];
      const float* GxT = Gx_l[t & 1];
      char* pub = exg + ((t + 1) & 3) * SLOTB + rank * 512;
      float hn2[2][2];
#pragma unroll
      for (int bsel = 0; bsel < 2; ++bsel) {
        const int m = m0 + 8 * bsel;
#pragma unroll
        for (int u = 0; u < 2; ++u) {
          const int gi_ = m * 16 + cp + u;
          float r = sigmf(GxT[gi_] + GhT[gi_] + bir[u]);
          float z = sigmf(GxT[256 + gi_] + GhT[256 + gi_] + biz[u]);
          float pren = GxT[512 + gi_] + bin_[u] + r * (GhT[512 + gi_] + bh2[u]);
          float n = 2.f / (1.f + __expf(-2.f * pren)) - 1.f;
          hn2[bsel][u] = (1.f - z) * n + z * hreg[bsel][u];
          hreg[bsel][u] = hn2[bsel][u];
        }
        _Float16 q0 = (_Float16)hn2[bsel][0], q1 = (_Float16)hn2[bsel][1];
        unsigned pu = ((unsigned)*(unsigned short*)&q1 << 16) | *(unsigned short*)&q0;
        __hip_atomic_store((unsigned*)(pub + m * 32 + cp * 2), pu, __ATOMIC_RELAXED,
                           __HIP_MEMORY_SCOPE_AGENT);
      }
      // out stores after the publishes (off the critical path)
#pragma unroll
      for (int bsel = 0; bsel < 2; ++bsel) {
        const int b = g * GB + m0 + 8 * bsel;
        *(float2*)(out + ((size_t)b * TLEN + t) * HDIM + c0 + cp) =
            make_float2(hn2[bsel][0], hn2[bsel][1]);
      }
    }
  }

  // carry output: final h
  if (wid == 0) {
#pragma unroll
    for (int bsel = 0; bsel < 2; ++bsel) {
      const int b = g * GB + m0 + 8 * bsel;
      *(float2*)(out + (size_t)BSZ * TLEN * HDIM + (size_t)b * HDIM + c0 + cp) =
          make_float2(hreg[bsel][0], hreg[bsel][1]);
    }
  }
}

extern "C" void kernel_launch(void* const* d_in, const int* in_sizes, int n_in,
                              void* d_out, int out_size, void* d_ws, size_t ws_size,
                              hipStream_t stream) {
  const float* x = (const float*)d_in[0];
  const float* Wi = (const float*)d_in[1];
  const float* bi = (const float*)d_in[2];
  const float* Wh = (const float*)d_in[3];
  const float* bhn = (const float*)d_in[4];
  float* out = (float*)d_out;

  // ws layout (bytes): xb 33554432 | exch 262144  (total 33.8MB, proven-safe)
  char* ws = (char*)d_ws;
  _Float16* xb = (_Float16*)ws;
  char* exch = ws + 33554432;

  gru_setup<<<4096, 256, 0, stream>>>(x, xb, (unsigned*)exch);
  gru_rec<<<NGRP * PBLK, 192, 0, stream>>>(xb, Wi, Wh, bi, bhn, exch, out);
}

// Round 8
// 1713.113 us; speedup vs baseline: 5.0146x; 1.2686x over previous
//
#include <hip/hip_runtime.h>

// GRU (Flax GRUCell), B=64 T=512 D=512 H=512, fp32 in/out, fp16 MFMA compute.
//
// 4 groups x 16 batches x 32 blocks. Per-step h exchange via SENTINEL-CODED
// DATA POLLING on the sc1/agent transport (r6/r7-proven): |h|<1 strictly, so
// fp16 0x4000 (2.0) is unreachable; readers poll the exchange data itself
// until sentinel-free. 4-slot rotation; owner resets its own region 2 slots
// ahead (causally ordered via barrier-drain + observed-publish chain).
// r8 change: ONLY WAVE 1 POLLS (r7 had all 3 gate waves redundantly polling
// the same 16KB slot -> ~20 TB/s of self-inflicted fabric congestion, 94% of
// each step spent waiting). Wave 1 stages the polled A-fragments into a
// 16KB XOR-swizzled LDS buffer; gate waves ds_read them after a barrier.
// x-GEMM runs before the poll. Poll loops bounded -> never a hang.
// Block: 192 thr; w0=combine+publish, w1=poll+stage, w2=slot reset; all
// waves run both GEMM halves. 128 blocks x 124KB LDS -> 1 block/CU.

#define BSZ 64
#define TLEN 512
#define DDIM 512
#define HDIM 512
#define NGRP 4
#define PBLK 32
#define GB 16
#define SLOTB 16384   // bytes per slot per group: 32 ranks * 512B
#define GRPB 65536    // 4 slots
#define SENT32 0x40004000u
#define GUARD (1 << 16)

typedef _Float16 half8 __attribute__((ext_vector_type(8)));
typedef _Float16 half4v __attribute__((ext_vector_type(4)));
typedef float f32x4 __attribute__((ext_vector_type(4)));

__device__ __forceinline__ float sigmf(float v) { return 1.f / (1.f + __expf(-v)); }

// ---------------- setup: x fp32->fp16; fill exchange with sentinel
__global__ void gru_setup(const float* __restrict__ x, _Float16* __restrict__ xb,
                          unsigned* __restrict__ exch) {
  size_t gid = (size_t)blockIdx.x * blockDim.x + threadIdx.x;
  size_t stride = (size_t)gridDim.x * blockDim.x;
  const float4* x4 = (const float4*)x;
  size_t nx4 = (size_t)BSZ * TLEN * DDIM / 4;
  for (size_t i = gid; i < nx4; i += stride) {
    float4 v = x4[i];
    half4v o = {(_Float16)v.x, (_Float16)v.y, (_Float16)v.z, (_Float16)v.w};
    *(half4v*)(xb + 4 * i) = o;
  }
  for (size_t i = gid; i < (size_t)NGRP * GRPB / 4; i += stride) exch[i] = SENT32;
}

// dirty-chunk mask: dword low half == sentinel? (each 4B writer store covers
// 2 fp16 atomically, so per-dword low-half check is partial-write-safe)
__device__ __forceinline__ unsigned chk16(const half8* ah) {
  unsigned dirty = 0;
#pragma unroll
  for (int kt = 0; kt < 16; ++kt) {
    uint4 c;
    __builtin_memcpy(&c, &ah[kt], 16);
    unsigned bad = ((c.x & 0xFFFFu) == 0x4000u) | ((c.y & 0xFFFFu) == 0x4000u) |
                   ((c.z & 0xFFFFu) == 0x4000u) | ((c.w & 0xFFFFu) == 0x4000u);
    dirty |= bad << kt;
  }
  return dirty;
}

// ---------------- recurrence
__global__ __launch_bounds__(192, 1) void gru_rec(
    const _Float16* __restrict__ xb, const float* __restrict__ Wi,
    const float* __restrict__ Wh, const float* __restrict__ bi,
    const float* __restrict__ bhn, char* __restrict__ exch,
    float* __restrict__ out) {
  // LDS: weights 2x48KB + Ah staging 16KB + gate tiles 2x2x3KB = 124KB
  __shared__ _Float16 Wh_l[48 * 512];
  __shared__ _Float16 Wi_l[48 * 512];
  __shared__ _Float16 Ah_l[16 * 512];
  __shared__ float Gh_l[2][3 * 256];
  __shared__ float Gx_l[2][3 * 256];

  const int tid = threadIdx.x;
  const int lane = tid & 63;
  const int wid = tid >> 6;  // gate index; also role index
  const int g = blockIdx.x >> 5;
  const int rank = blockIdx.x & 31;
  const int c0 = rank * 16;
  char* const exg = exch + (size_t)g * GRPB;

  // --- one-time in-kernel weight transpose+convert into swizzled LDS
  // element k of row r at byte (r<<10) | (((k>>3)<<4)^((r&7)<<4)) | ((k&7)<<1)
  for (int idx = tid; idx < 48 * 512; idx += 192) {
    int k = idx / 48;
    int r = idx - k * 48;
    int gate = r >> 4, j = r & 15;
    int col = gate * 512 + c0 + j;
    int phys = (r << 10) | ((((k >> 3) << 4) ^ ((r & 7) << 4))) | ((k & 7) << 1);
    *(_Float16*)((char*)Wi_l + phys) = (_Float16)Wi[(size_t)k * 1536 + col];
    *(_Float16*)((char*)Wh_l + phys) = (_Float16)Wh[(size_t)k * 1536 + col];
  }

  // combine-lane mapping (wave0): batches {m0, m0+8}, cols {cp, cp+1}
  const int m0 = lane >> 3;       // 0..7
  const int cp = (lane & 7) * 2;  // 0,2,...,14
  float bir[2], biz[2], bin_[2], bh2[2];
#pragma unroll
  for (int u = 0; u < 2; ++u) {
    bir[u] = bi[c0 + cp + u];
    biz[u] = bi[512 + c0 + cp + u];
    bin_[u] = bi[1024 + c0 + cp + u];
    bh2[u] = bhn[c0 + cp + u];
  }
  float hreg[2][2] = {{0.f, 0.f}, {0.f, 0.f}};
  __syncthreads();  // weights staged

  const int ar = lane & 15;  // A row (batch) / B col-in-slice
  const int kg = lane >> 4;  // k-group
  const int wrow = wid * 16 + ar;
  const int mbat = g * GB + ar;
  const _Float16* const xrow = xb + (size_t)mbat * (TLEN * DDIM);
  // exchange chunk kt for lane (ar,kg): hbase + slot*SLOTB + kt*1024
  char* const hbase = exg + ((kg >> 1) * 512 + ar * 32 + (kg & 1) * 16);
  // LDS A-fragment address for (ar,kg,kt): h[ar][kt*32+kg*8], XOR-swizzled
  const int abase = ar << 10;
  const int axor = (ar & 7) << 4;

  for (int t = 0; t < TLEN; ++t) {
    // a. x fragments + x-GEMM (all waves; before the poll)
    half8 a_x[16];
    const half8* xs = (const half8*)(xrow + (size_t)t * DDIM);
#pragma unroll
    for (int kt = 0; kt < 16; ++kt) a_x[kt] = xs[kt * 4 + kg];
    f32x4 acc_x = {0.f, 0.f, 0.f, 0.f};
#pragma unroll
    for (int kt = 0; kt < 16; ++kt) {
      const int off = (((kt * 4 + kg) << 4) ^ axor);
      half8 b_i = *(const half8*)((const char*)Wi_l + (wrow << 10) + off);
      acc_x = __builtin_amdgcn_mfma_f32_16x16x32_f16(a_x[kt], b_i, acc_x, 0, 0, 0);
    }

    // b. roles: w2 resets slot t+2 (drained at barrier1); w1 polls + stages
    if (wid == 2) {
      unsigned* rst = (unsigned*)(exg + ((t + 2) & 3) * SLOTB + rank * 512);
      __hip_atomic_store(rst + lane, SENT32, __ATOMIC_RELAXED, __HIP_MEMORY_SCOPE_AGENT);
      __hip_atomic_store(rst + 64 + lane, SENT32, __ATOMIC_RELAXED,
                         __HIP_MEMORY_SCOPE_AGENT);
    }
    if (wid == 1 && t > 0) {
      char* hb = hbase + (t & 3) * SLOTB;
      const char* p0 = hb;
      const char* p1 = hb + 4096;
      const char* p2 = hb + 8192;
      const char* p3 = hb + 12288;
      half8 ah[16];
      unsigned dirty;
      int guard = 0;
      do {  // fully-pipelined sweep: 16 loads, ONE vmcnt(0) (r7-proven)
        asm volatile(
            "global_load_dwordx4 %0,  %16, off sc1\n\t"
            "global_load_dwordx4 %1,  %16, off offset:1024 sc1\n\t"
            "global_load_dwordx4 %2,  %16, off offset:2048 sc1\n\t"
            "global_load_dwordx4 %3,  %16, off offset:3072 sc1\n\t"
            "global_load_dwordx4 %4,  %17, off sc1\n\t"
            "global_load_dwordx4 %5,  %17, off offset:1024 sc1\n\t"
            "global_load_dwordx4 %6,  %17, off offset:2048 sc1\n\t"
            "global_load_dwordx4 %7,  %17, off offset:3072 sc1\n\t"
            "global_load_dwordx4 %8,  %18, off sc1\n\t"
            "global_load_dwordx4 %9,  %18, off offset:1024 sc1\n\t"
            "global_load_dwordx4 %10, %18, off offset:2048 sc1\n\t"
            "global_load_dwordx4 %11, %18, off offset:3072 sc1\n\t"
            "global_load_dwordx4 %12, %19, off sc1\n\t"
            "global_load_dwordx4 %13, %19, off offset:1024 sc1\n\t"
            "global_load_dwordx4 %14, %19, off offset:2048 sc1\n\t"
            "global_load_dwordx4 %15, %19, off offset:3072 sc1\n\t"
            "s_waitcnt vmcnt(0)"
            : "=&v"(ah[0]), "=&v"(ah[1]), "=&v"(ah[2]), "=&v"(ah[3]),
              "=&v"(ah[4]), "=&v"(ah[5]), "=&v"(ah[6]), "=&v"(ah[7]),
              "=&v"(ah[8]), "=&v"(ah[9]), "=&v"(ah[10]), "=&v"(ah[11]),
              "=&v"(ah[12]), "=&v"(ah[13]), "=&v"(ah[14]), "=&v"(ah[15])
            : "v"(p0), "v"(p1), "v"(p2), "v"(p3));
        dirty = chk16(ah);
      } while (__any(dirty != 0u) && ++guard < GUARD);  // bounded: no hang
      // stage to LDS (swizzled, conflict-free; same mapping gate waves read)
#pragma unroll
      for (int kt = 0; kt < 16; ++kt) {
        *(half8*)((char*)Ah_l + (abase | ((kt * 64 + kg * 16) ^ axor))) = ah[kt];
      }
    }
    __syncthreads();  // barrier1: Ah_l ready (and w2's resets drained)

    // d. h-GEMM from LDS fragments
    f32x4 acc_h = {0.f, 0.f, 0.f, 0.f};
    if (t > 0) {
#pragma unroll
      for (int kt = 0; kt < 16; ++kt) {
        half8 a_h = *(const half8*)((const char*)Ah_l +
                                    (abase | ((kt * 64 + kg * 16) ^ axor)));
        const int off = (((kt * 4 + kg) << 4) ^ axor);
        half8 b_h = *(const half8*)((const char*)Wh_l + (wrow << 10) + off);
        acc_h = __builtin_amdgcn_mfma_f32_16x16x32_f16(a_h, b_h, acc_h, 0, 0, 0);
      }
    }
    // publish gate tiles (double-buffered; D layout col=ar, row=kg*4+q)
#pragma unroll
    for (int q = 0; q < 4; ++q) {
      int row = kg * 4 + q;
      Gh_l[t & 1][wid * 256 + row * 16 + ar] = acc_h[q];
      Gx_l[t & 1][wid * 256 + row * 16 + ar] = acc_x[q];
    }
    __syncthreads();  // barrier2: gates(t) ready

    // f. combine + publish (wave 0): fire-and-forget sentinel-coded data
    if (wid == 0) {
      const float* GhT = Gh_l[t & 1];
      const float* GxT = Gx_l[t & 1];
      char* pub = exg + ((t + 1) & 3) * SLOTB + rank * 512;
      float hn2[2][2];
#pragma unroll
      for (int bsel = 0; bsel < 2; ++bsel) {
        const int m = m0 + 8 * bsel;
#pragma unroll
        for (int u = 0; u < 2; ++u) {
          const int gi_ = m * 16 + cp + u;
          float r = sigmf(GxT[gi_] + GhT[gi_] + bir[u]);
          float z = sigmf(GxT[256 + gi_] + GhT[256 + gi_] + biz[u]);
          float pren = GxT[512 + gi_] + bin_[u] + r * (GhT[512 + gi_] + bh2[u]);
          float n = 2.f / (1.f + __expf(-2.f * pren)) - 1.f;
          hn2[bsel][u] = (1.f - z) * n + z * hreg[bsel][u];
          hreg[bsel][u] = hn2[bsel][u];
        }
        _Float16 q0 = (_Float16)hn2[bsel][0], q1 = (_Float16)hn2[bsel][1];
        unsigned pu = ((unsigned)*(unsigned short*)&q1 << 16) | *(unsigned short*)&q0;
        __hip_atomic_store((unsigned*)(pub + m * 32 + cp * 2), pu, __ATOMIC_RELAXED,
                           __HIP_MEMORY_SCOPE_AGENT);
      }
      // out stores after the publishes (off the critical path)
#pragma unroll
      for (int bsel = 0; bsel < 2; ++bsel) {
        const int b = g * GB + m0 + 8 * bsel;
        *(float2*)(out + ((size_t)b * TLEN + t) * HDIM + c0 + cp) =
            make_float2(hn2[bsel][0], hn2[bsel][1]);
      }
    }
  }

  // carry output: final h
  if (wid == 0) {
#pragma unroll
    for (int bsel = 0; bsel < 2; ++bsel) {
      const int b = g * GB + m0 + 8 * bsel;
      *(float2*)(out + (size_t)BSZ * TLEN * HDIM + (size_t)b * HDIM + c0 + cp) =
          make_float2(hreg[bsel][0], hreg[bsel][1]);
    }
  }
}

extern "C" void kernel_launch(void* const* d_in, const int* in_sizes, int n_in,
                              void* d_out, int out_size, void* d_ws, size_t ws_size,
                              hipStream_t stream) {
  const float* x = (const float*)d_in[0];
  const float* Wi = (const float*)d_in[1];
  const float* bi = (const float*)d_in[2];
  const float* Wh = (const float*)d_in[3];
  const float* bhn = (const float*)d_in[4];
  float* out = (float*)d_out;

  // ws layout (bytes): xb 33554432 | exch 262144  (total 33.8MB, proven-safe)
  char* ws = (char*)d_ws;
  _Float16* xb = (_Float16*)ws;
  char* exch = ws + 33554432;

  gru_setup<<<4096, 256, 0, stream>>>(x, xb, (unsigned*)exch);
  gru_rec<<<NGRP * PBLK, 192, 0, stream>>>(xb, Wi, Wh, bi, bhn, exch, out);
}